// Round 1
// baseline (303.386 us; speedup 1.0000x reference)
//
#include <hip/hip_runtime.h>

// ---------------------------------------------------------------------------
// NeuralCellularAutomata fused pipeline for MI355X (gfx950) — v5
//   state[128,64,40,40] -> sobel perception(192) -> w1 GEMM(512) -> LN(sample)
//   -> ReLU -> w2 GEMM(64) -> mask*alive gate -> residual add
// LN stats via Gram trick (Sx = colsumP.colw1, Sxx = <w1'w1, P'P>); X1 never
// materialized. v5: latency attack — (1) LDS exactly 40960 B -> 4 blocks/CU
// (gate in VGPRs, Ys o-chunk 64); (2) w1/w2/ln repacked into MFMA-fragment
// panel layouts so every k4 global load is a single coalesced 1KB wave read;
// (3) per-chunk prefetch of ln + w2 fragments ahead of the GEMM1 MFMA chain.
// ---------------------------------------------------------------------------

typedef unsigned short u16;
typedef unsigned int   u32;
typedef __attribute__((ext_vector_type(8))) u16    ushort8;
typedef __attribute__((ext_vector_type(4))) u16    u16x4;
typedef __attribute__((ext_vector_type(8))) __bf16 bf16x8;
typedef __attribute__((ext_vector_type(4))) float  f32x4;
typedef __attribute__((ext_vector_type(4))) u32    u32x4;

#define NB   128
#define NC   64
#define K1   192
#define NO   512
#define NHW  1600
#define LN_N 819200.0f

__device__ __forceinline__ u16 f2bf(float f) {
    union { float f; u32 u; } v; v.f = f;
    u32 u = v.u;
    u32 r = u + 0x7fffu + ((u >> 16) & 1u);   // round-nearest-even
    return (u16)(r >> 16);
}
__device__ __forceinline__ float bf2f(u16 h) {
    union { u32 u; float f; } v; v.u = ((u32)h) << 16; return v.f;
}
__device__ __forceinline__ float bfhi(u32 c) {   // float from high bf16
    union { u32 u; float f; } v; v.u = c & 0xffff0000u; return v.f;
}
__device__ __forceinline__ float bflo(u32 c) {   // float from low bf16
    union { u32 u; float f; } v; v.u = c << 16; return v.f;
}
__device__ __forceinline__ f32x4 mfma16(bf16x8 a, bf16x8 b, f32x4 c) {
    return __builtin_amdgcn_mfma_f32_16x16x32_bf16(a, b, c, 0, 0, 0);
}
__device__ __forceinline__ bf16x8 ldfrag(const u16* p) {
    return *(const bf16x8*)p;
}

// Shared perception helpers so k2_stats and k4_fused produce IDENTICAL bf16 P.
__device__ __forceinline__ void load_halo(const float* __restrict__ base, int h,
                                          int wq, float reg[3][12]) {
#pragma unroll
    for (int jj = 0; jj < 3; ++jj) {
        int hh = h + jj - 1;
        bool vh = (unsigned)hh < 40u;
        const float* rowp = base + hh * 40;
#pragma unroll
        for (int i = 0; i < 12; ++i) {
            int col = wq * 10 - 1 + i;
            reg[jj][i] = (vh && (unsigned)col < 40u) ? rowp[col] : 0.0f;
        }
    }
}
__device__ __forceinline__ void sobel_px(const float reg[3][12], int t,
                                         float& sx, float& sy, float& idn) {
    sx = (reg[0][t + 2] - reg[0][t]) + 2.0f * (reg[1][t + 2] - reg[1][t])
       + (reg[2][t + 2] - reg[2][t]);
    sy = (reg[2][t] + 2.0f * reg[2][t + 1] + reg[2][t + 2])
       - (reg[0][t] + 2.0f * reg[0][t + 1] + reg[0][t + 2]);
    idn = reg[1][t + 1];
}

// --- k0a: pack w1 -> panel layout w1p + transposed w1T; w2 -> panel w2p -----
// w1p panel (f=o/16, ks=k/32): element lane=(quad(k)<<4)|(o&15), j=k&7:
//   w1p[((f*6+ks)*64+lane)*8+j]  -> wave reads A-frag as lane*16B (coalesced)
// w2p panel (wid=s/16, oc=o/64, ks2): lane=(quad(o)<<4)|(s&15), j=o&7.
__global__ __launch_bounds__(256) void k0_convert(const float* __restrict__ w1,
                                                  const float* __restrict__ w2,
                                                  u16* __restrict__ w1p,
                                                  u16* __restrict__ w1T,
                                                  u16* __restrict__ w2p,
                                                  float* __restrict__ stats) {
    int g = blockIdx.x * 256 + threadIdx.x;
    if (g < NO * K1) {
        u16 v = f2bf(w1[g]);
        int o = g / K1, k = g - o * K1;
        int f = o >> 4, ks = k >> 5;
        int lane = (((k >> 3) & 3) << 4) | (o & 15);
        w1p[(size_t)(((f * 6 + ks) * 64 + lane) * 8 + (k & 7))] = v;
        w1T[(size_t)k * NO + o] = v;
    } else if (g < NO * K1 + NC * NO) {
        int i = g - NO * K1;
        int s = i / NO, o = i - s * NO;
        u16 v = f2bf(w2[i]);
        int wid = s >> 4, oc = o >> 6, ks2 = (o >> 5) & 1;
        int lane = (((o >> 3) & 3) << 4) | (s & 15);
        w2p[(size_t)((((wid * 8 + oc) * 2 + ks2) * 64 + lane) * 8 + (o & 7))] = v;
    } else if (g < NO * K1 + NC * NO + 256) {
        stats[g - NO * K1 - NC * NO] = 0.0f;
    }
}

// --- k0l: pack ln params into C-fragment panel order ------------------------
// lnp[(((bx*8+oc)*4+wid)*5+mi)*256 + lane*4 + r] = (bf16(lnb)<<16)|bf16(lnw)
//   where p = bx*80+mi*16+(lane&15), o = oc*64+wid*16+(lane>>4)*4+r.
__global__ __launch_bounds__(256) void k0_lncomb(const float* __restrict__ lnw,
                                                 const float* __restrict__ lnb,
                                                 u32* __restrict__ lnp) {
    int g = blockIdx.x * 256 + threadIdx.x;   // over 1600*512
    int r = g & 3;
    int lane = (g >> 2) & 63;
    int rest = g >> 8;
    int mi = rest % 5;  rest /= 5;
    int wid = rest & 3; rest >>= 2;
    int oc = rest & 7;
    int bx = rest >> 3;
    int p = bx * 80 + mi * 16 + (lane & 15);
    int o = oc * 64 + wid * 16 + ((lane >> 4) << 2) + r;
    size_t gi = (size_t)o * NHW + p;
    lnp[g] = ((u32)f2bf(lnb[gi]) << 16) | f2bf(lnw[gi]);
}

// --- k0g: G = w1^T w1 via MFMA (blocks 0..35); colw1 (block 36) -------------
__global__ __launch_bounds__(256) void k0_gram(const u16* __restrict__ w1T,
                                               float* __restrict__ G,
                                               float* __restrict__ colw1) {
    const int blk = blockIdx.x;
    const int tid = threadIdx.x;
    const int lane = tid & 63, wid = tid >> 6;
    const int q = lane >> 4, l15 = lane & 15;
    if (blk < 36) {
        int bj = blk / 6, bk = blk - bj * 6;
        int j0 = bj * 32 + (wid & 1) * 16, k0 = bk * 32 + (wid >> 1) * 16;
        f32x4 acc = {0.f, 0.f, 0.f, 0.f};
#pragma unroll
        for (int ks = 0; ks < 16; ++ks) {
            bf16x8 a  = ldfrag(&w1T[(size_t)(j0 + l15) * NO + ks * 32 + q * 8]);
            bf16x8 bb = ldfrag(&w1T[(size_t)(k0 + l15) * NO + ks * 32 + q * 8]);
            acc = mfma16(a, bb, acc);
        }
#pragma unroll
        for (int r = 0; r < 4; ++r)
            G[(size_t)(j0 + q * 4 + r) * K1 + k0 + l15] = acc[r];
    } else if (tid < K1) {
        float s = 0.f;
        for (int i = 0; i < NO / 8; ++i) {
            ushort8 v = *(const ushort8*)&w1T[(size_t)tid * NO + i * 8];
#pragma unroll
            for (int j = 0; j < 8; ++j) s += bf2f(v[j]);
        }
        colw1[tid] = s;
    }
}

// --- k2: per-sample LN stats via Gram MFMA ----------------------------------
__global__ __launch_bounds__(256) void k2_stats(const float* __restrict__ state,
                                                const float* __restrict__ G,
                                                const float* __restrict__ colw1,
                                                float* __restrict__ stats) {
    const int b = blockIdx.x >> 2, quarter = blockIdx.x & 3;
    const int tid = threadIdx.x;
    const int lane = tid & 63, wid = tid >> 6;
    const int q = lane >> 4, l15 = lane & 15;
    const int j0 = (wid & 1) * 96, j1 = (wid >> 1) * 96, jo = wid * 48;

    __shared__ __align__(16) u16 Pt[208 * 104];   // 43264 B
    __shared__ float red[8];

    for (int i = tid; i < 208 * 104 / 2; i += 256) ((u32*)Pt)[i] = 0u;
    __syncthreads();
    if (tid < 80) Pt[192 * 104 + tid] = 0x3F80u;  // ones row (bf16 1.0)

    f32x4 acc[6][6], accO[3];
#pragma unroll
    for (int i = 0; i < 6; ++i)
#pragma unroll
        for (int j = 0; j < 6; ++j) { f32x4 z = {0.f,0.f,0.f,0.f}; acc[i][j] = z; }
#pragma unroll
    for (int j = 0; j < 3; ++j) { f32x4 z = {0.f,0.f,0.f,0.f}; accO[j] = z; }

    const int c = tid >> 2, wq = tid & 3;
    const float* base = state + ((size_t)b * NC + c) * NHW;

    for (int tile = 0; tile < 5; ++tile) {
        const int h0 = (quarter * 5 + tile) * 2;
        __syncthreads();                           // prev MFMA reads done
        for (int rr = 0; rr < 2; ++rr) {
            float reg[3][12];
            load_halo(base, h0 + rr, wq, reg);
#pragma unroll
            for (int t = 0; t < 10; ++t) {
                float sx, sy, idn; sobel_px(reg, t, sx, sy, idn);
                int px = rr * 40 + wq * 10 + t;
                Pt[(3 * c + 0) * 104 + px] = f2bf(sx);
                Pt[(3 * c + 1) * 104 + px] = f2bf(sy);
                Pt[(3 * c + 2) * 104 + px] = f2bf(idn);
            }
        }
        __syncthreads();
#pragma unroll
        for (int ks = 0; ks < 3; ++ks) {
            bf16x8 av[6], bv[6], ao, bo[3];
#pragma unroll
            for (int fi = 0; fi < 6; ++fi)
                av[fi] = ldfrag(&Pt[(j0 + fi * 16 + l15) * 104 + ks * 32 + q * 8]);
#pragma unroll
            for (int fj = 0; fj < 6; ++fj)
                bv[fj] = ldfrag(&Pt[(j1 + fj * 16 + l15) * 104 + ks * 32 + q * 8]);
            ao = ldfrag(&Pt[(192 + l15) * 104 + ks * 32 + q * 8]);
#pragma unroll
            for (int fj = 0; fj < 3; ++fj)
                bo[fj] = ldfrag(&Pt[(jo + fj * 16 + l15) * 104 + ks * 32 + q * 8]);
#pragma unroll
            for (int fi = 0; fi < 6; ++fi)
#pragma unroll
                for (int fj = 0; fj < 6; ++fj)
                    acc[fi][fj] = mfma16(av[fi], bv[fj], acc[fi][fj]);
#pragma unroll
            for (int fj = 0; fj < 3; ++fj)
                accO[fj] = mfma16(ao, bo[fj], accO[fj]);
        }
    }

    float ssq = 0.f;
#pragma unroll
    for (int fi = 0; fi < 6; ++fi)
#pragma unroll
        for (int fj = 0; fj < 6; ++fj) {
            f32x4 gv = *(const f32x4*)&G[(size_t)(j1 + fj * 16 + l15) * K1
                                         + j0 + fi * 16 + q * 4];
#pragma unroll
            for (int r = 0; r < 4; ++r) ssq += acc[fi][fj][r] * gv[r];
        }
    float sm = 0.f;
    if (q == 0) {
#pragma unroll
        for (int fj = 0; fj < 3; ++fj)
            sm += accO[fj][0] * colw1[jo + fj * 16 + l15];
    }
#pragma unroll
    for (int off = 32; off > 0; off >>= 1) {
        ssq += __shfl_down(ssq, off);
        sm  += __shfl_down(sm, off);
    }
    if (lane == 0) { red[wid] = ssq; red[4 + wid] = sm; }
    __syncthreads();
    if (tid == 0) {
        atomicAdd(&stats[b * 2],     red[4] + red[5] + red[6] + red[7]);
        atomicAdd(&stats[b * 2 + 1], red[0] + red[1] + red[2] + red[3]);
    }
}

// --- k3: finalize per-sample mu / rsigma ------------------------------------
__global__ void k3_finalize(const float* __restrict__ stats, float2* __restrict__ musig) {
    int t = threadIdx.x;
    if (t < NB) {
        float s = stats[2 * t], qq = stats[2 * t + 1];
        float inv = 1.0f / LN_N;
        float mu = s * inv;
        float var = qq * inv - mu * mu;
        float2 r; r.x = mu; r.y = rsqrtf(var + 1e-5f);
        musig[t] = r;
    }
}

// --- k4: fused percept -> GEMM1 -> LN/ReLU -> GEMM2 -> gate+residual --------
// Block: 80 px x one sample. o in 8 chunks of 64; wave o-tile 16.
// GEMM1 D[o][p] (A=w1p panels, B=Pt LDS); transform via lnp panel u32x4;
// Ys b64 swizzled; GEMM2 D[s][p] (A=w2p panels, B=Ys). LDS = 40960 B exactly
// -> 4 blocks/CU with __launch_bounds__(256,4). Gate kept in VGPRs.
__global__ __launch_bounds__(256, 4) void k4_fused(const float* __restrict__ state,
                                                   const u16* __restrict__ w1p,
                                                   const u16* __restrict__ w2p,
                                                   const u32* __restrict__ lnp,
                                                   const int* __restrict__ mask,
                                                   const float2* __restrict__ musig,
                                                   float* __restrict__ out) {
    const int bx = blockIdx.x;                    // 0..19
    const int b  = blockIdx.y;
    const int p0 = bx * 80, h0 = bx * 2;
    const int tid = threadIdx.x;
    const int lane = tid & 63, wid = tid >> 6;
    const int q = lane >> 4, l15 = lane & 15;

    __shared__ __align__(16) u16 Pt[80 * 192];    // 30720 B
    __shared__ __align__(16) u16 Ys[80 * 64];     // 10240 B [p][o-chunk] swizzled

    const float2 ms = musig[b];
    const float mu = ms.x, rs = ms.y;
    const float murs = mu * rs;

    // perception -> Pt [p][192], group-of-8 XOR swizzle on 16B units
    {
        const int c = tid >> 2, wq = tid & 3;
        const float* base = state + ((size_t)b * NC + c) * NHW;
        for (int rr = 0; rr < 2; ++rr) {
            float reg[3][12];
            load_halo(base, h0 + rr, wq, reg);
#pragma unroll
            for (int t = 0; t < 10; ++t) {
                float sx, sy, idn; sobel_px(reg, t, sx, sy, idn);
                int px = rr * 40 + wq * 10 + t;
                int k = 3 * c;
#pragma unroll
                for (int i = 0; i < 3; ++i) {
                    int kk = k + i, u = kk >> 3;
                    int elem = px * 192 + (((u & 0x18) | ((u ^ px) & 7)) << 3) + (kk & 7);
                    Pt[elem] = f2bf(i == 0 ? sx : (i == 1 ? sy : idn));
                }
            }
        }
    }
    // gate in VGPRs: g5[mi] for p = p0 + mi*16 + l15
    float g5[5];
    {
        const float* st3 = state + ((size_t)b * NC + 3) * NHW;
#pragma unroll
        for (int mi = 0; mi < 5; ++mi) {
            int p = p0 + mi * 16 + l15;
            int h = p / 40, w = p - h * 40;
            float mx = -1e30f;
#pragma unroll
            for (int dh = -1; dh <= 1; ++dh) {
                int hh = h + dh;
                if ((unsigned)hh < 40u)
#pragma unroll
                    for (int dw = -1; dw <= 1; ++dw) {
                        int wc = w + dw;
                        if ((unsigned)wc < 40u) mx = fmaxf(mx, st3[hh * 40 + wc]);
                    }
            }
            g5[mi] = (mx > 0.1f && mask[p] != 0) ? 1.0f : 0.0f;
        }
    }
    __syncthreads();

    f32x4 acc2[5];
#pragma unroll
    for (int i = 0; i < 5; ++i) { f32x4 z = {0.f,0.f,0.f,0.f}; acc2[i] = z; }

    for (int oc = 0; oc < 8; ++oc) {
        // prefetch ln C-fragments (panel layout: lane*16B, coalesced)
        u32x4 lv[5];
        {
            const u32* lb = lnp + ((((size_t)bx * 8 + oc) * 4 + wid) * 5) * 256 + lane * 4;
#pragma unroll
            for (int mi = 0; mi < 5; ++mi)
                lv[mi] = *(const u32x4*)(lb + mi * 256);
        }
        // prefetch w2 A-frags for this chunk (panel layout, coalesced)
        const u16* w2base = w2p + ((size_t)(wid * 8 + oc) * 2) * 512 + lane * 8;
        bf16x8 aw0 = ldfrag(w2base);
        bf16x8 aw1 = ldfrag(w2base + 512);

        // ---- GEMM1: D[o][p], wave o-tile 16 ----
        f32x4 acc1[5];
#pragma unroll
        for (int i = 0; i < 5; ++i) { f32x4 z = {0.f,0.f,0.f,0.f}; acc1[i] = z; }
        const u16* w1base = w1p + ((size_t)(oc * 4 + wid) * 6) * 512 + lane * 8;
#pragma unroll
        for (int ks = 0; ks < 6; ++ks) {
            bf16x8 a = ldfrag(w1base + ks * 512);
#pragma unroll
            for (int mi = 0; mi < 5; ++mi) {
                int r = mi * 16 + l15, u = ks * 4 + q;
                bf16x8 bp = ldfrag(&Pt[r * 192 + (((u & 0x18) | ((u ^ r) & 7)) << 3)]);
                acc1[mi] = mfma16(a, bp, acc1[mi]);
            }
        }
        // ---- transform: Y = relu((x-mu)*rs*lnw + lnb) -> Ys b64 swizzled ----
#pragma unroll
        for (int mi = 0; mi < 5; ++mi) {
            int p = mi * 16 + l15;
            u16x4 yv;
#pragma unroll
            for (int r = 0; r < 4; ++r) {
                u32 cc = lv[mi][r];
                float t = fmaf(acc1[mi][r], rs, -murs);
                float y = fmaf(t, bflo(cc), bfhi(cc));
                yv[r] = f2bf(fmaxf(y, 0.0f));
            }
            int u = wid * 2 + (q >> 1);
            int up = u ^ (p & 7);
            *(u16x4*)&Ys[p * 64 + up * 8 + (q & 1) * 4] = yv;
        }
        __syncthreads();
        // ---- GEMM2 partial: D[s][p] += w2[s][o64] * Ys[o64][p] ----
#pragma unroll
        for (int ks2 = 0; ks2 < 2; ++ks2) {
            bf16x8 aw = ks2 ? aw1 : aw0;
#pragma unroll
            for (int mi = 0; mi < 5; ++mi) {
                int p = mi * 16 + l15;
                int u = ks2 * 4 + q;
                int up = u ^ (p & 7);
                bf16x8 by = ldfrag(&Ys[p * 64 + up * 8]);
                acc2[mi] = mfma16(aw, by, acc2[mi]);
            }
        }
        __syncthreads();                          // Ys reads done before rewrite
    }

    // ---- epilogue: direct gated residual stores ----
#pragma unroll
    for (int mi = 0; mi < 5; ++mi) {
        int p = p0 + mi * 16 + l15;
        float g = g5[mi];
#pragma unroll
        for (int r = 0; r < 4; ++r) {
            int s = wid * 16 + q * 4 + r;
            size_t idx = ((size_t)b * NC + s) * NHW + p;
            out[idx] = state[idx] + g * acc2[mi][r];
        }
    }
}

// ---------------------------------------------------------------------------
extern "C" void kernel_launch(void* const* d_in, const int* in_sizes, int n_in,
                              void* d_out, int out_size, void* d_ws, size_t ws_size,
                              hipStream_t stream) {
    const float* state = (const float*)d_in[0];
    const float* w1    = (const float*)d_in[1];
    const float* lnw   = (const float*)d_in[2];
    const float* lnb   = (const float*)d_in[3];
    const float* w2    = (const float*)d_in[4];
    const int*   mask  = (const int*)d_in[5];
    float* out = (float*)d_out;

    char* ws = (char*)d_ws;
    // workspace layout (total ~3.89 MB):
    u16*    w1p   = (u16*)(ws + 0ull);          //   196,608  panel layout
    u16*    w2p   = (u16*)(ws + 196608ull);     //    65,536  panel layout
    u32*    lnp   = (u32*)(ws + 262144ull);     // 3,276,800  panel (lnb|lnw)
    u16*    w1T   = (u16*)(ws + 3538944ull);    //   196,608  [k][o]
    float*  G     = (float*)(ws + 3735552ull);  //   147,456  w1^T w1
    float*  colw1 = (float*)(ws + 3883008ull);  //       768
    float*  stats = (float*)(ws + 3883776ull);  //     1,024  (sum,sumsq)*128
    float2* musig = (float2*)(ws + 3884800ull); //     1,024

    k0_convert <<<513, 256, 0, stream>>>(w1, w2, w1p, w1T, w2p, stats);
    k0_lncomb  <<<3200, 256, 0, stream>>>(lnw, lnb, lnp);
    k0_gram    <<<37, 256, 0, stream>>>(w1T, G, colw1);
    k2_stats   <<<512, 256, 0, stream>>>(state, G, colw1, stats);
    k3_finalize<<<1, 128, 0, stream>>>(stats, musig);
    k4_fused   <<<dim3(20, 128), 256, 0, stream>>>(state, w1p, w2p, lnp,
                                                   mask, musig, out);
}